// Round 18
// baseline (118.274 us; speedup 1.0000x reference)
//
#include <hip/hip_runtime.h>
#include <hip/hip_bf16.h>

#define N_    8
#define C_    256
#define K_    7
#define HID_  10
#define OUTC_ 60
#define S_    16384
#define BN_EPS 1e-5f

// ---- workspace layout (float offsets, all 16B-aligned) ----
#define OFF_PP     0        // pool partials: [512 slice][256 c][8 k] = 1048576
#define OFF_DP     1048576  // den partials: [512 slice][8] = 4096
#define OFF_EB     1052672  // 64
#define OFF_WB16   1052736  // bf16 weight frag images: 8n x 24576 ush = 98304 fl
#define OFF_M2B    1151040  // bf16 M2 images: 8n x 640 ush = 2560 fl
#define OFF_TOT    1153600  // BN sums: [120] -> pad 128 (zeroed by k_center)
#define OFF_Y16    1153728  // pre-BN y bf16: N*60*S ush = 3932160 fl
// total ~5.09M floats ~= 20.3 MB

#define GLDS(g, l) __builtin_amdgcn_global_load_lds( \
    (const __attribute__((address_space(1))) unsigned int*)(g), \
    (__attribute__((address_space(3))) unsigned int*)(l), 16, 0, 0)

typedef __attribute__((ext_vector_type(8))) short bfrag;   // 8 bf16 = 4 VGPR
typedef __attribute__((ext_vector_type(4))) float f32x4;   // MFMA acc

static __device__ __forceinline__ unsigned short f2bf(float f) {
    __hip_bfloat16 h = __float2bfloat16(f);
    return *reinterpret_cast<unsigned short*>(&h);
}
static __device__ __forceinline__ float bfh2f(unsigned int u) {   // high 16 bits
    return __builtin_bit_cast(float, u & 0xffff0000u);
}
static __device__ __forceinline__ float bfl2f(unsigned int u) {   // low 16 bits
    return __builtin_bit_cast(float, u << 16);
}

// -------- kernel A: fused class-softmax + MFMA pooling GEMM ----------------
// 1024 blocks xcd-chunked; block = (n, 256-px slice, 128-c half).
// LDS ~24.3KB -> 4 blocks/CU (grid-limited); 2-deep fea load pipeline.
__global__ void __launch_bounds__(256) k_pool(
        const float* __restrict__ fea, const float* __restrict__ seg,
        float* __restrict__ pp, float* __restrict__ dp) {
    int g = blockIdx.x;
    int lin = (g & 7) * 128 + (g >> 3);
    int n = lin >> 7, r = lin & 127;
    int sl = r >> 1, h2 = r & 1;
    int c0 = h2 * 128;
    int px0 = sl * 256;
    int tid = threadIdx.x, lane = tid & 63, wv = tid >> 6;
    int r15 = lane & 15, kg = (lane >> 4) << 3, pg = (lane >> 4) << 2;

    __shared__ unsigned short attT[16 * 256];       // [k][px] bf16 (8 KB)
    __shared__ unsigned short feaB[2][128 * 32];    // [c][px] bf16 (2x8 KB)
    __shared__ float red[4][8];

    // phase 1: per-px class softmax (thread = px); den partials from h2==0 only
    {
        const float* sp = seg + (size_t)n * K_ * S_ + px0 + tid;
        float e[K_], mx = -1e30f;
#pragma unroll
        for (int k = 0; k < K_; k++) { e[k] = sp[(size_t)k * S_]; mx = fmaxf(mx, e[k]); }
        float sum = 0.f;
#pragma unroll
        for (int k = 0; k < K_; k++) { e[k] = __expf(e[k] - mx); sum += e[k]; }
        float inv = 1.f / sum;
#pragma unroll
        for (int k = 0; k < K_; k++) {
            e[k] *= inv;
            attT[k * 256 + tid] = f2bf(e[k]);
        }
#pragma unroll
        for (int k = 0; k < K_; k++) {
            float v = e[k];
            for (int off = 32; off; off >>= 1) v += __shfl_xor(v, off, 64);
            if (lane == 0) red[wv][k] = v;
        }
    }

    const float* fb = fea + ((size_t)n * C_ + c0) * S_ + px0;
    int pq4 = (tid & 7) * 4;                        // px-quad within 32-px chunk
    int crow = tid >> 3;                            // c row (0..31) per round

    auto ldc = [&](int ch, float4* s) {
#pragma unroll
        for (int rr = 0; rr < 4; rr++)
            s[rr] = *(const float4*)(fb + (size_t)(rr * 32 + crow) * S_ + ch * 32 + pq4);
    };
    auto wrc = [&](int buf, const float4* s) {
#pragma unroll
        for (int rr = 0; rr < 4; rr++) {
            unsigned int u0 = (unsigned int)f2bf(s[rr].x) | ((unsigned int)f2bf(s[rr].y) << 16);
            unsigned int u1 = (unsigned int)f2bf(s[rr].z) | ((unsigned int)f2bf(s[rr].w) << 16);
            *(uint2*)&feaB[buf][(rr * 32 + crow) * 32 + pq4] = make_uint2(u0, u1);
        }
    };

    float4 A[4], B[4];
    ldc(0, A);
    wrc(0, A);               // waits A (older); nothing else outstanding
    ldc(1, B);               // in flight across first barrier
    __syncthreads();
    if (h2 == 0 && tid < K_)
        dp[(size_t)(n * 64 + sl) * 8 + tid] =
            red[0][tid] + red[1][tid] + red[2][tid] + red[3][tid];

    f32x4 acc[2];
    acc[0] = (f32x4)0.f; acc[1] = (f32x4)0.f;

#pragma unroll
    for (int ch = 0; ch < 8; ch++) {
        if (ch > 0) {
            asm volatile("s_waitcnt lgkmcnt(0)" ::: "memory");
            __builtin_amdgcn_s_barrier();
        }
        float4* issue = (ch & 1) ? B : A;    // buffer freed after write below
        float4* wsrc2 = (ch & 1) ? A : B;    // holds chunk ch+1
        if (ch < 6) ldc(ch + 2, issue);      // issue first: stays in flight
        if (ch < 7) wrc((ch + 1) & 1, wsrc2);// auto-vmcnt waits only older loads
        bfrag b = *(const bfrag*)&attT[r15 * 256 + ch * 32 + kg];
#pragma unroll
        for (int mt = 0; mt < 2; mt++) {
            bfrag a = *(const bfrag*)&feaB[ch & 1][(wv * 32 + mt * 16 + r15) * 32 + kg];
            acc[mt] = __builtin_amdgcn_mfma_f32_16x16x32_bf16(a, b, acc[mt], 0, 0, 0);
        }
    }

    // store per-slice num partials: D col = k (r15), row = c
    if (r15 < 8) {
#pragma unroll
        for (int mt = 0; mt < 2; mt++) {
#pragma unroll
            for (int rr = 0; rr < 4; rr++) {
                int c = c0 + wv * 32 + mt * 16 + pg + rr;
                pp[((size_t)(n * 64 + sl) * 256 + c) * 8 + r15] = acc[mt][rr];
            }
        }
    }
}

// ---- kernel B: reduce partials -> p_center -> bf16 weight/M2 frag images ----
// 64 blocks: 8 per n (pc/ql replicated, output work sliced); block 0 zeroes tot
__global__ void k_center(const float* __restrict__ pp, const float* __restrict__ dp,
                         const float* __restrict__ Wq, const float* __restrict__ bq,
                         const float* __restrict__ Wk, const float* __restrict__ bk,
                         const float* __restrict__ Wp,
                         float* __restrict__ eb, float* __restrict__ m2b,
                         float* __restrict__ wb16, float* __restrict__ tot) {
    int n = blockIdx.x >> 3, j = blockIdx.x & 7;
    int tid = threadIdx.x;
    if (blockIdx.x == 0 && tid < 128) tot[tid] = 0.f;
    __shared__ float pc[C_ * K_];     // [c][k]
    __shared__ float ql[HID_ * K_];   // [o][k]
    __shared__ float dinv[K_];
    if (tid < K_) {
        float d = 0.f;
        for (int s = 0; s < 64; s++) d += dp[(size_t)(n * 64 + s) * 8 + tid];
        dinv[tid] = 1.f / d;
    }
    __syncthreads();
    for (int i = tid; i < C_ * K_; i += 256) {
        int c = i / K_, k = i - c * K_;
        float v = 0.f;
        for (int s = 0; s < 64; s++)
            v += pp[((size_t)(n * 64 + s) * 256 + c) * 8 + k];
        pc[i] = v * dinv[k];
    }
    __syncthreads();
    if (tid < HID_ * K_) {
        int o = tid / K_, k = tid % K_;
        float s = bq[o];
        for (int c = 0; c < C_; c++) s += Wq[o * C_ + c] * pc[c * K_ + k];
        ql[tid] = s;
    }
    __syncthreads();
    // bf16 weight image slice: this block covers i in [j*3072, (j+1)*3072)
    unsigned short* wp16 = (unsigned short*)wb16 + (size_t)n * 24576;
    for (int i = j * 3072 + tid; i < (j + 1) * 3072; i += 256) {
        int ch = i / 6144, r = i - ch * 6144;
        int o = r / 72, jj = r - o * 72;
        float v = 0.f;
        if (o < 80 && jj < 64) {
            int c = ch * 64 + jj;
            if (o < 60) v = Wp[o * 2 * C_ + c];
            else if (o < 67) {
                int k = o - 60;
                for (int o2 = 0; o2 < HID_; o2++) v += ql[o2 * K_ + k] * Wk[o2 * C_ + c];
            }
        }
        wp16[i] = f2bf(v);
    }
    // bf16 M2 image slice: entries [j*80, (j+1)*80)
    unsigned short* mp16 = (unsigned short*)m2b + (size_t)n * 640;
    if (tid < 80) {
        int i = j * 80 + tid;
        int o = i >> 3, k = i & 7;
        float v = 0.f;
        if (k < 7 && o < 60) {
            for (int c = 0; c < C_; c++) v += Wp[o * 2 * C_ + C_ + c] * pc[c * K_ + k];
        }
        mp16[i] = f2bf(v);
    }
    if (j == 0 && tid < K_) {
        float s = 0.f;
        for (int o = 0; o < HID_; o++) s += ql[o * K_ + tid] * bk[o];
        eb[n * K_ + tid] = s;
    }
}

// ---------------- kernel C: MFMA fused energy/softmax/projection ----------------
// (round-17 form; BN partials now atomically accumulated into tot[120])
__global__ void __launch_bounds__(256) k_main(
        const float* __restrict__ fea, const float* __restrict__ wb16,
        const float* __restrict__ ebias, const float* __restrict__ m2b,
        unsigned short* __restrict__ y16, float* __restrict__ tot) {
    int g = blockIdx.x;
    int lin = (g & 7) * 128 + (g >> 3);
    int n = lin >> 7, tile = lin & 127;
    int tid = threadIdx.x, lane = tid & 63, wv = tid >> 6;
    int r15 = lane & 15, kg = (lane >> 4) << 3, pg = (lane >> 4) << 2;

    __shared__ unsigned short wlds[2][6144];   // weight chunk images (24 KB)
    __shared__ unsigned short feaT[2][9216];   // [128 px][72 c] bf16 (36 KB)
    __shared__ unsigned short abf[128 * 8];    // attention [px][8k] bf16
    __shared__ unsigned short m2l[640];        // M2 [80][8] bf16
    __shared__ float att_e[K_][128];
    __shared__ float ebl[8];
    __shared__ float redm[4][80];
    __shared__ float redq[4][80];

    const unsigned int* wsrc = (const unsigned int*)wb16 + (size_t)n * 12288;
    const unsigned int* m2s  = (const unsigned int*)m2b + (size_t)n * 320;
    for (int i = tid; i < 320; i += 256) ((unsigned int*)m2l)[i] = m2s[i];
    if (tid < K_) ebl[tid] = ebias[n * K_ + tid];

    const float* fbase = fea + (size_t)n * C_ * S_ + tile * 128;
    int cr2 = tid >> 3, h = tid & 7;           // c-pair + px-octant for staging

    f32x4 acc[5][2];
#pragma unroll
    for (int ot = 0; ot < 5; ot++) { acc[ot][0] = (f32x4)0.f; acc[ot][1] = (f32x4)0.f; }

    auto ldw = [&](int ch, int buf) {
#pragma unroll
        for (int rnd = 0; rnd < 3; rnd++)
            GLDS(wsrc + ch * 3072 + rnd * 1024 + wv * 256 + lane * 4,
                 &((unsigned int*)wlds[buf])[rnd * 1024 + wv * 256]);
    };
    auto ldfea = [&](int ch, float4* s0, float4* s1) {
        const float* bp = fbase + (size_t)(ch * 64 + cr2 * 2) * S_ + h * 16;
#pragma unroll
        for (int i = 0; i < 4; i++) s0[i] = *(const float4*)(bp + i * 4);
#pragma unroll
        for (int i = 0; i < 4; i++) s1[i] = *(const float4*)(bp + S_ + i * 4);
    };
    auto wrfea = [&](int buf, const float4* s0, const float4* s1) {
        unsigned int* dst = (unsigned int*)feaT[buf];
#pragma unroll
        for (int i = 0; i < 4; i++)
#pragma unroll
            for (int e = 0; e < 4; e++) {
                int px = h * 16 + i * 4 + e;
                dst[px * 36 + cr2] = (unsigned int)f2bf(((const float*)&s0[i])[e])
                                   | ((unsigned int)f2bf(((const float*)&s1[i])[e]) << 16);
            }
    };
    auto mfma = [&](int buf) {
        const unsigned short* fb = feaT[buf];
        const unsigned short* wb = wlds[buf];
#pragma unroll
        for (int ks = 0; ks < 2; ks++) {
            bfrag a0 = *(const bfrag*)&fb[(wv * 32 + r15) * 72 + ks * 32 + kg];
            bfrag a1 = *(const bfrag*)&fb[(wv * 32 + 16 + r15) * 72 + ks * 32 + kg];
#pragma unroll
            for (int ot = 0; ot < 5; ot++) {
                bfrag b = *(const bfrag*)&wb[(ot * 16 + r15) * 72 + ks * 32 + kg];
                acc[ot][0] = __builtin_amdgcn_mfma_f32_16x16x32_bf16(a0, b, acc[ot][0], 0, 0, 0);
                acc[ot][1] = __builtin_amdgcn_mfma_f32_16x16x32_bf16(a1, b, acc[ot][1], 0, 0, 0);
            }
        }
    };
#define WAITBAR(nvm) asm volatile("s_waitcnt vmcnt(" #nvm ") lgkmcnt(0)" ::: "memory"); \
                     __builtin_amdgcn_s_barrier();

    float4 A0[4], A1[4], B0[4], B1[4];
    ldw(0, 0);
    ldfea(0, A0, A1);
    ldfea(1, B0, B1);
    wrfea(0, A0, A1);
    WAITBAR(8)

    wrfea(1, B0, B1);
    ldw(1, 1);
    ldfea(2, A0, A1);
    mfma(0);
    WAITBAR(8)

    wrfea(0, A0, A1);
    ldw(2, 0);
    ldfea(3, B0, B1);
    mfma(1);
    WAITBAR(8)

    wrfea(1, B0, B1);
    ldw(3, 1);
    mfma(0);
    WAITBAR(0)

    mfma(1);
#undef WAITBAR

    // energies: cols 60..63 in out-tile 3 (local 12..15), 64..66 in tile 4 (local 0..2)
    if (r15 >= 12) {
        int k = r15 - 12;
#pragma unroll
        for (int pxt = 0; pxt < 2; pxt++)
#pragma unroll
            for (int r = 0; r < 4; r++)
                att_e[k][wv * 32 + pxt * 16 + pg + r] = acc[3][pxt][r];
    }
    if (r15 < 3) {
        int k = 4 + r15;
#pragma unroll
        for (int pxt = 0; pxt < 2; pxt++)
#pragma unroll
            for (int r = 0; r < 4; r++)
                att_e[k][wv * 32 + pxt * 16 + pg + r] = acc[4][pxt][r];
    }
    __syncthreads();
    if (tid < 128) {   // per-px class softmax -> bf16 attention fragments
        float e[K_], mx = -1e30f;
#pragma unroll
        for (int k = 0; k < K_; k++) { e[k] = att_e[k][tid] + ebl[k]; mx = fmaxf(mx, e[k]); }
        float sum = 0.f;
#pragma unroll
        for (int k = 0; k < K_; k++) { e[k] = __expf(e[k] - mx); sum += e[k]; }
        float inv = 1.f / sum;
        unsigned int* ab = (unsigned int*)abf;
        ab[tid * 4 + 0] = (unsigned int)f2bf(e[0] * inv) | ((unsigned int)f2bf(e[1] * inv) << 16);
        ab[tid * 4 + 1] = (unsigned int)f2bf(e[2] * inv) | ((unsigned int)f2bf(e[3] * inv) << 16);
        ab[tid * 4 + 2] = (unsigned int)f2bf(e[4] * inv) | ((unsigned int)f2bf(e[5] * inv) << 16);
        ab[tid * 4 + 3] = (unsigned int)f2bf(e[6] * inv);
    }
    __syncthreads();

    // y += M2 @ attention  (one K=32 MFMA, k>=8 lanes contribute zero)
    bfrag az = (bfrag)(short)0;
    bfrag a20 = az, a21 = az;
    if (lane < 16) {
        a20 = *(const bfrag*)&abf[(wv * 32 + r15) * 8];
        a21 = *(const bfrag*)&abf[(wv * 32 + 16 + r15) * 8];
    }
#pragma unroll
    for (int ot = 0; ot < 5; ot++) {
        bfrag b2 = az;
        if (lane < 16) b2 = *(const bfrag*)&m2l[(ot * 16 + r15) * 8];
        acc[ot][0] = __builtin_amdgcn_mfma_f32_16x16x32_bf16(a20, b2, acc[ot][0], 0, 0, 0);
        acc[ot][1] = __builtin_amdgcn_mfma_f32_16x16x32_bf16(a21, b2, acc[ot][1], 0, 0, 0);
    }

    // store pre-BN y as bf16 (cols < 60) + atomic BN sums (fp32)
    unsigned short* ybase = y16 + (size_t)n * OUTC_ * S_ + tile * 128 + wv * 32 + pg;
#pragma unroll
    for (int ot = 0; ot < 5; ot++) {
        int o = ot * 16 + r15;
        float sm_ = 0.f, sq_ = 0.f;
#pragma unroll
        for (int pxt = 0; pxt < 2; pxt++) {
            f32x4 v = acc[ot][pxt];
            if (o < OUTC_) {
                unsigned int u0 = (unsigned int)f2bf(v[0]) | ((unsigned int)f2bf(v[1]) << 16);
                unsigned int u1 = (unsigned int)f2bf(v[2]) | ((unsigned int)f2bf(v[3]) << 16);
                *(uint2*)(ybase + (size_t)o * S_ + pxt * 16) = make_uint2(u0, u1);
            }
            sm_ += v[0] + v[1] + v[2] + v[3];
            sq_ += v[0]*v[0] + v[1]*v[1] + v[2]*v[2] + v[3]*v[3];
        }
        sm_ += __shfl_xor(sm_, 16, 64); sm_ += __shfl_xor(sm_, 32, 64);
        sq_ += __shfl_xor(sq_, 16, 64); sq_ += __shfl_xor(sq_, 32, 64);
        if (lane < 16) { redm[wv][ot * 16 + lane] = sm_; redq[wv][ot * 16 + lane] = sq_; }
    }
    __syncthreads();
    if (tid < 120) {
        float s;
        if (tid < OUTC_)
            s = redm[0][tid] + redm[1][tid] + redm[2][tid] + redm[3][tid];
        else {
            int o = tid - OUTC_;
            s = redq[0][o] + redq[1][o] + redq[2][o] + redq[3][o];
        }
        atomicAdd(&tot[tid], s);
    }
}

// -------- kernel E: BN stats (from tot) + apply + ReLU (bf16 ws -> fp32 out) ----
__global__ void k_apply(const unsigned short* __restrict__ y16,
                        const float* __restrict__ tot,
                        const float* __restrict__ gamma, const float* __restrict__ beta,
                        float* __restrict__ out) {
    __shared__ float sscl[OUTC_], sshf[OUTC_];
    int tid = threadIdx.x;
    if (tid < OUTC_) {
        const float invn = 1.f / (float)(N_ * S_);
        float mean = tot[tid] * invn;
        float var = tot[60 + tid] * invn - mean * mean;
        float sc = gamma[tid] * rsqrtf(var + BN_EPS);
        sscl[tid] = sc;
        sshf[tid] = beta[tid] - mean * sc;
    }
    __syncthreads();
    int idx = blockIdx.x * 256 + tid;                  // 8-px unit
    int o = (idx >> 11) % OUTC_;
    uint4 v = ((const uint4*)y16)[idx];
    float a = sscl[o], b = sshf[o];
    float4 r0, r1;
    r0.x = fmaxf(bfl2f(v.x) * a + b, 0.f);
    r0.y = fmaxf(bfh2f(v.x) * a + b, 0.f);
    r0.z = fmaxf(bfl2f(v.y) * a + b, 0.f);
    r0.w = fmaxf(bfh2f(v.y) * a + b, 0.f);
    r1.x = fmaxf(bfl2f(v.z) * a + b, 0.f);
    r1.y = fmaxf(bfh2f(v.z) * a + b, 0.f);
    r1.z = fmaxf(bfl2f(v.w) * a + b, 0.f);
    r1.w = fmaxf(bfh2f(v.w) * a + b, 0.f);
    ((float4*)out)[idx * 2 + 0] = r0;
    ((float4*)out)[idx * 2 + 1] = r1;
}

extern "C" void kernel_launch(void* const* d_in, const int* in_sizes, int n_in,
                              void* d_out, int out_size, void* d_ws, size_t ws_size,
                              hipStream_t stream) {
    const float* p_fea = (const float*)d_in[0];
    const float* p_seg = (const float*)d_in[1];
    const float* Wq    = (const float*)d_in[2];
    const float* bq    = (const float*)d_in[3];
    const float* Wk    = (const float*)d_in[4];
    const float* bk    = (const float*)d_in[5];
    const float* Wp    = (const float*)d_in[6];
    const float* gamma = (const float*)d_in[7];
    const float* beta  = (const float*)d_in[8];

    float* ws   = (float*)d_ws;
    float* pp   = ws + OFF_PP;
    float* dp   = ws + OFF_DP;
    float* eb   = ws + OFF_EB;
    float* wb16 = ws + OFF_WB16;
    float* m2b  = ws + OFF_M2B;
    float* tot  = ws + OFF_TOT;
    unsigned short* y16 = (unsigned short*)(ws + OFF_Y16);
    float* ybuf = (float*)d_out;

    k_pool<<<1024, 256, 0, stream>>>(p_fea, p_seg, pp, dp);
    k_center<<<64, 256, 0, stream>>>(pp, dp, Wq, bq, Wk, bk, Wp, eb, m2b, wb16, tot);
    k_main<<<1024, 256, 0, stream>>>(p_fea, wb16, eb, m2b, y16, tot);
    k_apply<<<(N_ * OUTC_ * S_ / 8) / 256, 256, 0, stream>>>(y16, tot, gamma, beta, ybuf);
}

// Round 19
// 113.710 us; speedup vs baseline: 1.0401x; 1.0401x over previous
//
#include <hip/hip_runtime.h>
#include <hip/hip_bf16.h>

#define N_    8
#define C_    256
#define K_    7
#define HID_  10
#define OUTC_ 60
#define S_    16384
#define BN_EPS 1e-5f

// ---- workspace layout (float offsets, all 16B-aligned) ----
#define OFF_PP     0        // pool partials: [512 slice][256 c][8 k] = 1048576
#define OFF_DP     1048576  // den partials: [512 slice][8] = 4096
#define OFF_EB     1052672  // 64
#define OFF_WB16   1052736  // bf16 weight frag images: 8n x 24576 ush = 98304 fl
#define OFF_M2B    1151040  // bf16 M2 images: 8n x 640 ush = 2560 fl
#define OFF_PART   1153600  // 1024*120 = 122880
#define OFF_SCL    1276480  // 64
#define OFF_SHF    1276544  // 64
#define OFF_Y16    1276608  // pre-BN y bf16: N*60*S ush = 3932160 fl

#define GLDS(g, l) __builtin_amdgcn_global_load_lds( \
    (const __attribute__((address_space(1))) unsigned int*)(g), \
    (__attribute__((address_space(3))) unsigned int*)(l), 16, 0, 0)

typedef __attribute__((ext_vector_type(8))) short bfrag;   // 8 bf16 = 4 VGPR
typedef __attribute__((ext_vector_type(4))) float f32x4;   // MFMA acc

static __device__ __forceinline__ unsigned short f2bf(float f) {
    __hip_bfloat16 h = __float2bfloat16(f);
    return *reinterpret_cast<unsigned short*>(&h);
}
static __device__ __forceinline__ float bfh2f(unsigned int u) {   // high 16 bits
    return __builtin_bit_cast(float, u & 0xffff0000u);
}
static __device__ __forceinline__ float bfl2f(unsigned int u) {   // low 16 bits
    return __builtin_bit_cast(float, u << 16);
}

// -------- kernel A: fused class-softmax + MFMA pooling GEMM ----------------
// 512 blocks xcd-chunked; block = (n, 256-px slice). (round-12 proven form)
__global__ void __launch_bounds__(256) k_pool(
        const float* __restrict__ fea, const float* __restrict__ seg,
        float* __restrict__ pp, float* __restrict__ dp) {
    int g = blockIdx.x;
    int lin = (g & 7) * 64 + (g >> 3);
    int n = lin >> 6, sl = lin & 63;
    int tid = threadIdx.x, lane = tid & 63, wv = tid >> 6;
    int r15 = lane & 15, kg = (lane >> 4) << 3, pg = (lane >> 4) << 2;
    int px0 = sl * 256;

    __shared__ unsigned short attT[16 * 256];       // [k][px] bf16 (8 KB)
    __shared__ unsigned short feaB[2][256 * 32];    // [c][px] bf16 (2x16 KB)
    __shared__ float red[4][8];

    // phase 1: per-px class softmax (thread = px), den partials (fp32)
    {
        const float* sp = seg + (size_t)n * K_ * S_ + px0 + tid;
        float e[K_], mx = -1e30f;
#pragma unroll
        for (int k = 0; k < K_; k++) { e[k] = sp[(size_t)k * S_]; mx = fmaxf(mx, e[k]); }
        float sum = 0.f;
#pragma unroll
        for (int k = 0; k < K_; k++) { e[k] = __expf(e[k] - mx); sum += e[k]; }
        float inv = 1.f / sum;
#pragma unroll
        for (int k = 0; k < K_; k++) {
            e[k] *= inv;
            attT[k * 256 + tid] = f2bf(e[k]);
        }
#pragma unroll
        for (int k = 0; k < K_; k++) {
            float v = e[k];
            for (int off = 32; off; off >>= 1) v += __shfl_xor(v, off, 64);
            if (lane == 0) red[wv][k] = v;
        }
    }

    const float* fb = fea + (size_t)n * C_ * S_ + px0;
    int pq4 = (tid & 7) * 4;                        // px-quad within 32-px chunk
    int crow = tid >> 3;                            // c row offset within round

    // stage chunk 0
    {
        float4 s[8];
#pragma unroll
        for (int rr = 0; rr < 8; rr++)
            s[rr] = *(const float4*)(fb + (size_t)(rr * 32 + crow) * S_ + pq4);
#pragma unroll
        for (int rr = 0; rr < 8; rr++) {
            unsigned int u0 = (unsigned int)f2bf(s[rr].x) | ((unsigned int)f2bf(s[rr].y) << 16);
            unsigned int u1 = (unsigned int)f2bf(s[rr].z) | ((unsigned int)f2bf(s[rr].w) << 16);
            *(uint2*)&feaB[0][(rr * 32 + crow) * 32 + pq4] = make_uint2(u0, u1);
        }
    }
    __syncthreads();
    if (tid < K_)
        dp[(size_t)lin * 8 + tid] = red[0][tid] + red[1][tid] + red[2][tid] + red[3][tid];

    f32x4 acc[4];
#pragma unroll
    for (int mt = 0; mt < 4; mt++) acc[mt] = (f32x4)0.f;

#pragma unroll
    for (int ch = 0; ch < 8; ch++) {
        int cur = ch & 1;
        float4 s[8];
        if (ch < 7) {
#pragma unroll
            for (int rr = 0; rr < 8; rr++)
                s[rr] = *(const float4*)(fb + (size_t)(rr * 32 + crow) * S_ + (ch + 1) * 32 + pq4);
        }
        // MFMA on current chunk: 4 c-tiles per wave, K=32 px
        bfrag b = *(const bfrag*)&attT[r15 * 256 + ch * 32 + kg];
#pragma unroll
        for (int mt = 0; mt < 4; mt++) {
            bfrag a = *(const bfrag*)&feaB[cur][(wv * 64 + mt * 16 + r15) * 32 + kg];
            acc[mt] = __builtin_amdgcn_mfma_f32_16x16x32_bf16(a, b, acc[mt], 0, 0, 0);
        }
        if (ch < 7) {
#pragma unroll
            for (int rr = 0; rr < 8; rr++) {
                unsigned int u0 = (unsigned int)f2bf(s[rr].x) | ((unsigned int)f2bf(s[rr].y) << 16);
                unsigned int u1 = (unsigned int)f2bf(s[rr].z) | ((unsigned int)f2bf(s[rr].w) << 16);
                *(uint2*)&feaB[cur ^ 1][(rr * 32 + crow) * 32 + pq4] = make_uint2(u0, u1);
            }
        }
        __syncthreads();
    }

    // store per-slice num partials: D col = k (r15), row = c (pg+r within tile)
    if (r15 < K_) {
#pragma unroll
        for (int mt = 0; mt < 4; mt++) {
#pragma unroll
            for (int r = 0; r < 4; r++) {
                int c = wv * 64 + mt * 16 + pg + r;
                pp[((size_t)lin * 256 + c) * 8 + r15] = acc[mt][r];
            }
        }
    }
}

// ---- kernel B: reduce partials -> p_center -> bf16 weight/M2 frag images ----
// 64 blocks: 8 per n (pc/ql replicated, output work sliced)
__global__ void k_center(const float* __restrict__ pp, const float* __restrict__ dp,
                         const float* __restrict__ Wq, const float* __restrict__ bq,
                         const float* __restrict__ Wk, const float* __restrict__ bk,
                         const float* __restrict__ Wp,
                         float* __restrict__ eb, float* __restrict__ m2b,
                         float* __restrict__ wb16) {
    int n = blockIdx.x >> 3, j = blockIdx.x & 7;
    int tid = threadIdx.x;
    __shared__ float pc[C_ * K_];     // [c][k]
    __shared__ float ql[HID_ * K_];   // [o][k]
    __shared__ float dinv[K_];
    if (tid < K_) {
        float d = 0.f;
        for (int s = 0; s < 64; s++) d += dp[(size_t)(n * 64 + s) * 8 + tid];
        dinv[tid] = 1.f / d;
    }
    __syncthreads();
    for (int i = tid; i < C_ * K_; i += 256) {
        int c = i / K_, k = i - c * K_;
        float v = 0.f;
        for (int s = 0; s < 64; s++)
            v += pp[((size_t)(n * 64 + s) * 256 + c) * 8 + k];
        pc[i] = v * dinv[k];
    }
    __syncthreads();
    if (tid < HID_ * K_) {
        int o = tid / K_, k = tid % K_;
        float s = bq[o];
        for (int c = 0; c < C_; c++) s += Wq[o * C_ + c] * pc[c * K_ + k];
        ql[tid] = s;
    }
    __syncthreads();
    // bf16 weight image slice: this block covers i in [j*3072, (j+1)*3072)
    unsigned short* wp16 = (unsigned short*)wb16 + (size_t)n * 24576;
    for (int i = j * 3072 + tid; i < (j + 1) * 3072; i += 256) {
        int ch = i / 6144, r = i - ch * 6144;
        int o = r / 72, jj = r - o * 72;
        float v = 0.f;
        if (o < 80 && jj < 64) {
            int c = ch * 64 + jj;
            if (o < 60) v = Wp[o * 2 * C_ + c];
            else if (o < 67) {
                int k = o - 60;
                for (int o2 = 0; o2 < HID_; o2++) v += ql[o2 * K_ + k] * Wk[o2 * C_ + c];
            }
        }
        wp16[i] = f2bf(v);
    }
    // bf16 M2 image slice: entries [j*80, (j+1)*80)
    unsigned short* mp16 = (unsigned short*)m2b + (size_t)n * 640;
    if (tid < 80) {
        int i = j * 80 + tid;
        int o = i >> 3, k = i & 7;
        float v = 0.f;
        if (k < 7 && o < 60) {
            for (int c = 0; c < C_; c++) v += Wp[o * 2 * C_ + C_ + c] * pc[c * K_ + k];
        }
        mp16[i] = f2bf(v);
    }
    if (j == 0 && tid < K_) {
        float s = 0.f;
        for (int o = 0; o < HID_; o++) s += ql[o * K_ + tid] * bk[o];
        eb[n * K_ + tid] = s;
    }
}

// ---------------- kernel C: MFMA fused energy/softmax/projection ----------------
// 1024 blocks xcd-chunked; 128 px/block; 2-chunk-deep fea register pipeline,
// counted vmcnt(8) keeps the 8 fea prefetch loads in flight across barriers.
__global__ void __launch_bounds__(256) k_main(
        const float* __restrict__ fea, const float* __restrict__ wb16,
        const float* __restrict__ ebias, const float* __restrict__ m2b,
        unsigned short* __restrict__ y16, float* __restrict__ part) {
    int g = blockIdx.x;
    int lin = (g & 7) * 128 + (g >> 3);
    int n = lin >> 7, tile = lin & 127;
    int tid = threadIdx.x, lane = tid & 63, wv = tid >> 6;
    int r15 = lane & 15, kg = (lane >> 4) << 3, pg = (lane >> 4) << 2;

    __shared__ unsigned short wlds[2][6144];   // weight chunk images (24 KB)
    __shared__ unsigned short feaT[2][9216];   // [128 px][72 c] bf16 (36 KB)
    __shared__ unsigned short abf[128 * 8];    // attention [px][8k] bf16
    __shared__ unsigned short m2l[640];        // M2 [80][8] bf16
    __shared__ float att_e[K_][128];
    __shared__ float ebl[8];
    __shared__ float redm[4][80];
    __shared__ float redq[4][80];

    const unsigned int* wsrc = (const unsigned int*)wb16 + (size_t)n * 12288;
    const unsigned int* m2s  = (const unsigned int*)m2b + (size_t)n * 320;
    for (int i = tid; i < 320; i += 256) ((unsigned int*)m2l)[i] = m2s[i];
    if (tid < K_) ebl[tid] = ebias[n * K_ + tid];

    const float* fbase = fea + (size_t)n * C_ * S_ + tile * 128;
    int cr2 = tid >> 3, h = tid & 7;           // c-pair + px-octant for staging

    f32x4 acc[5][2];
#pragma unroll
    for (int ot = 0; ot < 5; ot++) { acc[ot][0] = (f32x4)0.f; acc[ot][1] = (f32x4)0.f; }

    auto ldw = [&](int ch, int buf) {
#pragma unroll
        for (int rnd = 0; rnd < 3; rnd++)
            GLDS(wsrc + ch * 3072 + rnd * 1024 + wv * 256 + lane * 4,
                 &((unsigned int*)wlds[buf])[rnd * 1024 + wv * 256]);
    };
    auto ldfea = [&](int ch, float4* s0, float4* s1) {
        const float* bp = fbase + (size_t)(ch * 64 + cr2 * 2) * S_ + h * 16;
#pragma unroll
        for (int i = 0; i < 4; i++) s0[i] = *(const float4*)(bp + i * 4);
#pragma unroll
        for (int i = 0; i < 4; i++) s1[i] = *(const float4*)(bp + S_ + i * 4);
    };
    auto wrfea = [&](int buf, const float4* s0, const float4* s1) {
        unsigned int* dst = (unsigned int*)feaT[buf];
#pragma unroll
        for (int i = 0; i < 4; i++)
#pragma unroll
            for (int e = 0; e < 4; e++) {
                int px = h * 16 + i * 4 + e;
                dst[px * 36 + cr2] = (unsigned int)f2bf(((const float*)&s0[i])[e])
                                   | ((unsigned int)f2bf(((const float*)&s1[i])[e]) << 16);
            }
    };
    auto mfma = [&](int buf) {
        const unsigned short* fb = feaT[buf];
        const unsigned short* wb = wlds[buf];
#pragma unroll
        for (int ks = 0; ks < 2; ks++) {
            bfrag a0 = *(const bfrag*)&fb[(wv * 32 + r15) * 72 + ks * 32 + kg];
            bfrag a1 = *(const bfrag*)&fb[(wv * 32 + 16 + r15) * 72 + ks * 32 + kg];
#pragma unroll
            for (int ot = 0; ot < 5; ot++) {
                bfrag b = *(const bfrag*)&wb[(ot * 16 + r15) * 72 + ks * 32 + kg];
                acc[ot][0] = __builtin_amdgcn_mfma_f32_16x16x32_bf16(a0, b, acc[ot][0], 0, 0, 0);
                acc[ot][1] = __builtin_amdgcn_mfma_f32_16x16x32_bf16(a1, b, acc[ot][1], 0, 0, 0);
            }
        }
    };
#define WAITBAR(nvm) asm volatile("s_waitcnt vmcnt(" #nvm ") lgkmcnt(0)" ::: "memory"); \
                     __builtin_amdgcn_s_barrier();

    float4 A0[4], A1[4], B0[4], B1[4];
    // prologue: w[0] GLDS; fea[0] -> feaT[0]; issue fea[1] (stays in flight)
    ldw(0, 0);
    ldfea(0, A0, A1);
    ldfea(1, B0, B1);
    wrfea(0, A0, A1);        // waits A regs (older than B) -> B stays outstanding
    WAITBAR(8)

    // ch 0
    wrfea(1, B0, B1);        // fea[1] -> feaT[1]
    ldw(1, 1);
    ldfea(2, A0, A1);        // issue fea[2]
    mfma(0);
    WAITBAR(8)

    // ch 1
    wrfea(0, A0, A1);        // fea[2] -> feaT[0]
    ldw(2, 0);
    ldfea(3, B0, B1);        // issue fea[3]
    mfma(1);
    WAITBAR(8)

    // ch 2
    wrfea(1, B0, B1);        // fea[3] -> feaT[1]
    ldw(3, 1);
    mfma(0);
    WAITBAR(0)

    // ch 3
    mfma(1);
#undef WAITBAR

    // energies: cols 60..63 in out-tile 3 (local 12..15), 64..66 in tile 4 (local 0..2)
    if (r15 >= 12) {
        int k = r15 - 12;
#pragma unroll
        for (int pxt = 0; pxt < 2; pxt++)
#pragma unroll
            for (int r = 0; r < 4; r++)
                att_e[k][wv * 32 + pxt * 16 + pg + r] = acc[3][pxt][r];
    }
    if (r15 < 3) {
        int k = 4 + r15;
#pragma unroll
        for (int pxt = 0; pxt < 2; pxt++)
#pragma unroll
            for (int r = 0; r < 4; r++)
                att_e[k][wv * 32 + pxt * 16 + pg + r] = acc[4][pxt][r];
    }
    __syncthreads();
    if (tid < 128) {   // per-px class softmax -> bf16 attention fragments
        float e[K_], mx = -1e30f;
#pragma unroll
        for (int k = 0; k < K_; k++) { e[k] = att_e[k][tid] + ebl[k]; mx = fmaxf(mx, e[k]); }
        float sum = 0.f;
#pragma unroll
        for (int k = 0; k < K_; k++) { e[k] = __expf(e[k] - mx); sum += e[k]; }
        float inv = 1.f / sum;
        unsigned int* ab = (unsigned int*)abf;
        ab[tid * 4 + 0] = (unsigned int)f2bf(e[0] * inv) | ((unsigned int)f2bf(e[1] * inv) << 16);
        ab[tid * 4 + 1] = (unsigned int)f2bf(e[2] * inv) | ((unsigned int)f2bf(e[3] * inv) << 16);
        ab[tid * 4 + 2] = (unsigned int)f2bf(e[4] * inv) | ((unsigned int)f2bf(e[5] * inv) << 16);
        ab[tid * 4 + 3] = (unsigned int)f2bf(e[6] * inv);
    }
    __syncthreads();

    // y += M2 @ attention  (one K=32 MFMA, k>=8 lanes contribute zero)
    bfrag az = (bfrag)(short)0;
    bfrag a20 = az, a21 = az;
    if (lane < 16) {
        a20 = *(const bfrag*)&abf[(wv * 32 + r15) * 8];
        a21 = *(const bfrag*)&abf[(wv * 32 + 16 + r15) * 8];
    }
#pragma unroll
    for (int ot = 0; ot < 5; ot++) {
        bfrag b2 = az;
        if (lane < 16) b2 = *(const bfrag*)&m2l[(ot * 16 + r15) * 8];
        acc[ot][0] = __builtin_amdgcn_mfma_f32_16x16x32_bf16(a20, b2, acc[ot][0], 0, 0, 0);
        acc[ot][1] = __builtin_amdgcn_mfma_f32_16x16x32_bf16(a21, b2, acc[ot][1], 0, 0, 0);
    }

    // store pre-BN y as bf16 (cols < 60) + per-block BN partials (fp32)
    unsigned short* ybase = y16 + (size_t)n * OUTC_ * S_ + tile * 128 + wv * 32 + pg;
#pragma unroll
    for (int ot = 0; ot < 5; ot++) {
        int o = ot * 16 + r15;
        float sm_ = 0.f, sq_ = 0.f;
#pragma unroll
        for (int pxt = 0; pxt < 2; pxt++) {
            f32x4 v = acc[ot][pxt];
            if (o < OUTC_) {
                unsigned int u0 = (unsigned int)f2bf(v[0]) | ((unsigned int)f2bf(v[1]) << 16);
                unsigned int u1 = (unsigned int)f2bf(v[2]) | ((unsigned int)f2bf(v[3]) << 16);
                *(uint2*)(ybase + (size_t)o * S_ + pxt * 16) = make_uint2(u0, u1);
            }
            sm_ += v[0] + v[1] + v[2] + v[3];
            sq_ += v[0]*v[0] + v[1]*v[1] + v[2]*v[2] + v[3]*v[3];
        }
        sm_ += __shfl_xor(sm_, 16, 64); sm_ += __shfl_xor(sm_, 32, 64);
        sq_ += __shfl_xor(sq_, 16, 64); sq_ += __shfl_xor(sq_, 32, 64);
        if (lane < 16) { redm[wv][ot * 16 + lane] = sm_; redq[wv][ot * 16 + lane] = sq_; }
    }
    __syncthreads();
    if (tid < 120) {
        float s;
        if (tid < OUTC_)
            s = redm[0][tid] + redm[1][tid] + redm[2][tid] + redm[3][tid];
        else {
            int o = tid - OUTC_;
            s = redq[0][o] + redq[1][o] + redq[2][o] + redq[3][o];
        }
        part[(size_t)g * 120 + tid] = s;
    }
}

// ---------------- kernel D: BN statistics ----------------
__global__ void k_bn(const float* __restrict__ part, const float* __restrict__ gamma,
                     const float* __restrict__ beta, float* __restrict__ scl,
                     float* __restrict__ shf) {
    int t = threadIdx.x & 127, q = threadIdx.x >> 7;   // 512 threads
    __shared__ float red[4][120];
    __shared__ float tot[120];
    if (t < 120) {
        float s = 0.f;
        for (int b = q * 256; b < q * 256 + 256; b++) s += part[(size_t)b * 120 + t];
        red[q][t] = s;
    }
    __syncthreads();
    if (threadIdx.x < 120)
        tot[threadIdx.x] = red[0][threadIdx.x] + red[1][threadIdx.x] +
                           red[2][threadIdx.x] + red[3][threadIdx.x];
    __syncthreads();
    if (threadIdx.x < OUTC_) {
        const float invn = 1.f / (float)(N_ * S_);
        float mean = tot[threadIdx.x] * invn;
        float var = tot[60 + threadIdx.x] * invn - mean * mean;
        float sc = gamma[threadIdx.x] * rsqrtf(var + BN_EPS);
        scl[threadIdx.x] = sc;
        shf[threadIdx.x] = beta[threadIdx.x] - mean * sc;
    }
}

// -------- kernel E: BN apply + ReLU (bf16 ws -> fp32 d_out) ----------------
__global__ void k_apply(const unsigned short* __restrict__ y16,
                        const float* __restrict__ scl, const float* __restrict__ shf,
                        float* __restrict__ out) {
    int idx = blockIdx.x * 256 + threadIdx.x;          // 8-px unit
    int o = (idx >> 11) % OUTC_;                        // (idx*8 / S) % 60
    uint4 v = ((const uint4*)y16)[idx];
    float a = scl[o], b = shf[o];
    float4 r0, r1;
    r0.x = fmaxf(bfl2f(v.x) * a + b, 0.f);
    r0.y = fmaxf(bfh2f(v.x) * a + b, 0.f);
    r0.z = fmaxf(bfl2f(v.y) * a + b, 0.f);
    r0.w = fmaxf(bfh2f(v.y) * a + b, 0.f);
    r1.x = fmaxf(bfl2f(v.z) * a + b, 0.f);
    r1.y = fmaxf(bfh2f(v.z) * a + b, 0.f);
    r1.z = fmaxf(bfl2f(v.w) * a + b, 0.f);
    r1.w = fmaxf(bfh2f(v.w) * a + b, 0.f);
    ((float4*)out)[idx * 2 + 0] = r0;
    ((float4*)out)[idx * 2 + 1] = r1;
}

extern "C" void kernel_launch(void* const* d_in, const int* in_sizes, int n_in,
                              void* d_out, int out_size, void* d_ws, size_t ws_size,
                              hipStream_t stream) {
    const float* p_fea = (const float*)d_in[0];
    const float* p_seg = (const float*)d_in[1];
    const float* Wq    = (const float*)d_in[2];
    const float* bq    = (const float*)d_in[3];
    const float* Wk    = (const float*)d_in[4];
    const float* bk    = (const float*)d_in[5];
    const float* Wp    = (const float*)d_in[6];
    const float* gamma = (const float*)d_in[7];
    const float* beta  = (const float*)d_in[8];

    float* ws   = (float*)d_ws;
    float* pp   = ws + OFF_PP;
    float* dp   = ws + OFF_DP;
    float* eb   = ws + OFF_EB;
    float* wb16 = ws + OFF_WB16;
    float* m2b  = ws + OFF_M2B;
    float* part = ws + OFF_PART;
    float* scl  = ws + OFF_SCL;
    float* shf  = ws + OFF_SHF;
    unsigned short* y16 = (unsigned short*)(ws + OFF_Y16);
    float* ybuf = (float*)d_out;

    k_pool<<<512, 256, 0, stream>>>(p_fea, p_seg, pp, dp);
    k_center<<<64, 256, 0, stream>>>(pp, dp, Wq, bq, Wk, bk, Wp, eb, m2b, wb16);
    k_main<<<1024, 256, 0, stream>>>(p_fea, wb16, eb, m2b, y16, part);
    k_bn<<<1, 512, 0, stream>>>(part, gamma, beta, scl, shf);
    k_apply<<<(N_ * OUTC_ * S_ / 8) / 256, 256, 0, stream>>>(y16, scl, shf, ybuf);
}